// Round 10
// baseline (111.504 us; speedup 1.0000x reference)
//
#include <hip/hip_runtime.h>
#include <math.h>

// TopK router via split-bf16 MFMA: logits = x @ W^T, top-2 + softmax.
// x = xh + xl (bf16 RTNE split), W likewise (preconverted to ws by wprep).
// logits = xh*wh + xh*wl + xl*wh (fp32 MFMA accumulate).
//
// Round-10: round-9 structure + T4 barrier fix. Per-chunk barrier is
// s_waitcnt lgkmcnt(0) + raw s_barrier (NO vmcnt drain) so the depth-3
// x prefetch stays in flight across barriers (m97 barrier-drain fix).
// grid 512 (2 blocks/CU), 512 thr = 8 waves, 32 tok/block.
// A (x) double-buffered swizzled LDS; B (W h/l) direct global (L2-hot).
// Wave = (kw k-window 0..3, eh expert-half 0..1): 2x2 tiles 16x16x32.

typedef float f32x4 __attribute__((ext_vector_type(4)));
typedef short bf16x8 __attribute__((ext_vector_type(8)));
typedef unsigned int u32;

#define NE 64
#define TOK 32
#define CK 128
#define THREADS 512
#define LDE 68

__device__ __forceinline__ u32 rtne_bf16(float f) {
  u32 u = __builtin_bit_cast(u32, f);
  return (u + 0x7FFFu + ((u >> 16) & 1u)) >> 16;
}
__device__ __forceinline__ float bf16_to_f(u32 h) {
  return __builtin_bit_cast(float, h << 16);
}
// LDS byte address: 256B rows (128 bf16), 16B block XOR-swizzled by row
__device__ __forceinline__ int lds_addr(int base, int row, int blk) {
  return base + row * 256 + ((blk ^ (row & 7)) << 4);
}
// barrier that publishes LDS writes but does NOT drain vmem prefetches
__device__ __forceinline__ void barrier_nodrain() {
  asm volatile("s_waitcnt lgkmcnt(0)" ::: "memory");
  __builtin_amdgcn_s_barrier();
}

__global__ __launch_bounds__(256)
void wprep(const float* __restrict__ Wg, uint2* __restrict__ Who,
           uint2* __restrict__ Wlo) {
  const int i = blockIdx.x * 256 + threadIdx.x;   // f32x4 index (65536 total)
  const f32x4 v = *((const f32x4*)Wg + i);
  const u32 h0 = rtne_bf16(v.x), h1 = rtne_bf16(v.y);
  const u32 h2 = rtne_bf16(v.z), h3 = rtne_bf16(v.w);
  const u32 l0 = rtne_bf16(v.x - bf16_to_f(h0));
  const u32 l1 = rtne_bf16(v.y - bf16_to_f(h1));
  const u32 l2 = rtne_bf16(v.z - bf16_to_f(h2));
  const u32 l3 = rtne_bf16(v.w - bf16_to_f(h3));
  Who[i] = make_uint2(h0 | (h1 << 16), h2 | (h3 << 16));
  Wlo[i] = make_uint2(l0 | (l1 << 16), l2 | (l3 << 16));
}

__global__ __launch_bounds__(THREADS, 4)
void gemm_topk(const float* __restrict__ x, const u32* __restrict__ Whg,
               const u32* __restrict__ Wlg, float* __restrict__ out_probs,
               float* __restrict__ out_idx, int D) {
  __shared__ __align__(16) char smem[32768];
  // A staging: buf0 h@0 l@8192, buf1 h@16384 l@24576 (32 rows x 256B each)

  const int tid = threadIdx.x;
  const int w   = tid >> 6;
  const int l   = tid & 63;
  const int kw  = w & 3;           // K32 window within chunk
  const int eh  = w >> 2;          // expert half (0/1)
  const int m0  = blockIdx.x * TOK;
  const int nCh = D / CK;          // 32
  const int Du  = D / 2;           // u32 per W row

  const int g   = l >> 4;          // k sub-group
  const int r16 = l & 15;

  // x staging map: thread -> (row=tid>>4, blk=tid&15); 8 f32 = one 16B bf16 blk
  const int xr = tid >> 4, xc = tid & 15;
  const float* xg = x + (size_t)(m0 + xr) * D + xc * 8;

  // B fragment base offsets (u32 units), L2-hot direct-global
  const u32* wh0 = Whg + (size_t)(eh * 32 + 0  + r16) * Du + kw * 16 + g * 4;
  const u32* wh1 = Whg + (size_t)(eh * 32 + 16 + r16) * Du + kw * 16 + g * 4;
  const u32* wl0 = Wlg + (size_t)(eh * 32 + 0  + r16) * Du + kw * 16 + g * 4;
  const u32* wl1 = Wlg + (size_t)(eh * 32 + 16 + r16) * Du + kw * 16 + g * 4;

  f32x4 acc[2][2];
#pragma unroll
  for (int m = 0; m < 2; ++m)
#pragma unroll
    for (int n = 0; n < 2; ++n) acc[m][n] = (f32x4){0.f, 0.f, 0.f, 0.f};

  // depth-3 x prefetch: xA = chunk c+1, xB = c+2, xC = c+3 (during iter c)
  f32x4 xA[2], xB[2], xC[2];

  xA[0] = __builtin_nontemporal_load((const f32x4*)(xg));
  xA[1] = __builtin_nontemporal_load((const f32x4*)(xg + 4));
  if (nCh > 1) {
    xB[0] = __builtin_nontemporal_load((const f32x4*)(xg + CK));
    xB[1] = __builtin_nontemporal_load((const f32x4*)(xg + CK + 4));
  }
  if (nCh > 2) {
    xC[0] = __builtin_nontemporal_load((const f32x4*)(xg + 2 * CK));
    xC[1] = __builtin_nontemporal_load((const f32x4*)(xg + 2 * CK + 4));
  }
  // convert + publish chunk 0
  {
    const float f[8] = {xA[0].x, xA[0].y, xA[0].z, xA[0].w,
                        xA[1].x, xA[1].y, xA[1].z, xA[1].w};
    u32 h[8], lo[8];
#pragma unroll
    for (int i = 0; i < 8; ++i) {
      h[i]  = rtne_bf16(f[i]);
      lo[i] = rtne_bf16(f[i] - bf16_to_f(h[i]));
    }
    *(uint4*)(smem + lds_addr(0,    xr, xc)) =
        make_uint4(h[0] | (h[1] << 16), h[2] | (h[3] << 16),
                   h[4] | (h[5] << 16), h[6] | (h[7] << 16));
    *(uint4*)(smem + lds_addr(8192, xr, xc)) =
        make_uint4(lo[0] | (lo[1] << 16), lo[2] | (lo[3] << 16),
                   lo[4] | (lo[5] << 16), lo[6] | (lo[7] << 16));
  }
  __syncthreads();                 // one full barrier pre-loop (cheap, once)
  xA[0] = xB[0]; xA[1] = xB[1];    // xA = chunk1
  xB[0] = xC[0]; xB[1] = xC[1];    // xB = chunk2

  for (int c = 0; c < nCh; ++c) {
    const int buf = (c & 1) * 16384;

    // issue chunk c+3 loads (in flight ~3 chunk phases)
    if (c + 3 < nCh) {
      const float* xn = xg + (size_t)(c + 3) * CK;
      xC[0] = __builtin_nontemporal_load((const f32x4*)(xn));
      xC[1] = __builtin_nontemporal_load((const f32x4*)(xn + 4));
    }

    // convert + write chunk c+1 into the other buffer
    if (c + 1 < nCh) {
      const float f[8] = {xA[0].x, xA[0].y, xA[0].z, xA[0].w,
                          xA[1].x, xA[1].y, xA[1].z, xA[1].w};
      u32 h[8], lo[8];
#pragma unroll
      for (int i = 0; i < 8; ++i) {
        h[i]  = rtne_bf16(f[i]);
        lo[i] = rtne_bf16(f[i] - bf16_to_f(h[i]));
      }
      *(uint4*)(smem + lds_addr((buf ^ 16384), xr, xc)) =
          make_uint4(h[0] | (h[1] << 16), h[2] | (h[3] << 16),
                     h[4] | (h[5] << 16), h[6] | (h[7] << 16));
      *(uint4*)(smem + lds_addr((buf ^ 16384) + 8192, xr, xc)) =
          make_uint4(lo[0] | (lo[1] << 16), lo[2] | (lo[3] << 16),
                     lo[4] | (lo[5] << 16), lo[6] | (lo[7] << 16));
    }

    // compute chunk c: A from LDS buf, B direct from global (L2-hot)
    const int blk = kw * 4 + g;
    bf16x8 ah[2], al_[2], bh[2], bl_[2];
#pragma unroll
    for (int m = 0; m < 2; ++m) {
      const int row = m * 16 + r16;
      ah[m]  = *(const bf16x8*)(smem + lds_addr(buf,        row, blk));
      al_[m] = *(const bf16x8*)(smem + lds_addr(buf + 8192, row, blk));
    }
    const size_t ko = (size_t)c * (CK / 2);
    bh[0]  = *(const bf16x8*)(wh0 + ko);
    bh[1]  = *(const bf16x8*)(wh1 + ko);
    bl_[0] = *(const bf16x8*)(wl0 + ko);
    bl_[1] = *(const bf16x8*)(wl1 + ko);
#pragma unroll
    for (int m = 0; m < 2; ++m)
#pragma unroll
      for (int n = 0; n < 2; ++n) {
        acc[m][n] = __builtin_amdgcn_mfma_f32_16x16x32_bf16(ah[m],  bh[n],  acc[m][n], 0, 0, 0);
        acc[m][n] = __builtin_amdgcn_mfma_f32_16x16x32_bf16(ah[m],  bl_[n], acc[m][n], 0, 0, 0);
        acc[m][n] = __builtin_amdgcn_mfma_f32_16x16x32_bf16(al_[m], bh[n],  acc[m][n], 0, 0, 0);
      }

    // publish c+1, keep x prefetches in flight (NO vmcnt drain)
    barrier_nodrain();
    xA[0] = xB[0]; xA[1] = xB[1];
    xB[0] = xC[0]; xB[1] = xC[1];
  }

  // ---- epilogue: reduce 4 k-windows, decode, top-2 ----
  float* R = (float*)smem;          // [8 waves][16 tr][64 lanes] = 32KB
#pragma unroll
  for (int m = 0; m < 2; ++m)
#pragma unroll
    for (int n = 0; n < 2; ++n)
#pragma unroll
      for (int r = 0; r < 4; ++r)
        R[w * 1024 + ((m * 2 + n) * 4 + r) * 64 + l] = acc[m][n][r];
  __syncthreads();

  // 32 tok x 64 exp = 2048 values; 512 threads x 4
  float vals[4];
  int dsti[4];
#pragma unroll
  for (int i = 0; i < 4; ++i) {
    const int j = tid + i * THREADS;
    const int t = j >> 6, e = j & 63;
    const int mm = t >> 4, nn = (e >> 4) & 1, ee = e >> 5;
    const int rr = t & 3;
    const int ll = ((t & 15) >> 2) * 16 + (e & 15);
    float v = 0.f;
#pragma unroll
    for (int k = 0; k < 4; ++k)
      v += R[(ee * 4 + k) * 1024 + ((mm * 2 + nn) * 4 + rr) * 64 + ll];
    vals[i] = v;
    dsti[i] = t * LDE + e;
  }
  __syncthreads();                  // reads done before aliasing writes
  float* Lf = (float*)smem;         // [32][68]
#pragma unroll
  for (int i = 0; i < 4; ++i) Lf[dsti[i]] = vals[i];
  __syncthreads();

  if (tid < TOK) {
    const float* row = &Lf[tid * LDE];
    float b0 = -INFINITY, b1 = -INFINITY;
    int i0 = 0, i1 = 0;
#pragma unroll
    for (int e = 0; e < NE; ++e) {   // strict '>' = lowest index on ties
      const float val = row[e];
      if (val > b0) { b1 = b0; i1 = i0; b0 = val; i0 = e; }
      else if (val > b1) { b1 = val; i1 = e; }
    }
    const float e1  = expf(b1 - b0);
    const float inv = 1.f / (1.f + e1);
    const int tok = m0 + tid;
    out_probs[tok * 2 + 0] = inv;
    out_probs[tok * 2 + 1] = e1 * inv;
    out_idx[tok * 2 + 0] = (float)i0;
    out_idx[tok * 2 + 1] = (float)i1;
  }
}

// ---- fallback (round-6 fused VALU kernel) if ws is too small ----
#define FEW 8
#define FCK 64
#define FLDT 68
#define FTOK 64
__global__ __launch_bounds__(512, 2)
void router_fused(const float* __restrict__ x, const float* __restrict__ W,
                  float* __restrict__ out_probs, float* __restrict__ out_idx,
                  int D) {
  __shared__ float As[2][FTOK][FLDT];
  const int tid = threadIdx.x;
  const int w = __builtin_amdgcn_readfirstlane(tid >> 6);
  const int lane = tid & 63;
  const int m0 = blockIdx.x * FTOK;
  const int nCh = D / FCK;
  const float* xrow = x + (size_t)(m0 + lane) * D;
  const float* __restrict__ wbase = W + (size_t)(w * FEW) * D;
  float acc[FEW];
#pragma unroll
  for (int e = 0; e < FEW; ++e) acc[e] = 0.f;
  {
    const f32x4 a = *reinterpret_cast<const f32x4*>(xrow + 4 * w);
    const f32x4 b = *reinterpret_cast<const f32x4*>(xrow + 4 * (w + 8));
    *reinterpret_cast<f32x4*>(&As[0][lane][4 * w]) = a;
    *reinterpret_cast<f32x4*>(&As[0][lane][4 * (w + 8)]) = b;
  }
  __syncthreads();
  for (int c = 0; c < nCh; ++c) {
    const int buf = c & 1;
    f32x4 na, nb;
    const bool more = (c + 1 < nCh);
    if (more) {
      const float* xn = xrow + (size_t)(c + 1) * FCK;
      na = *reinterpret_cast<const f32x4*>(xn + 4 * w);
      nb = *reinterpret_cast<const f32x4*>(xn + 4 * (w + 8));
    }
    const float* __restrict__ wp = wbase + (size_t)c * FCK;
#pragma unroll 2
    for (int kk = 0; kk < FCK / 4; ++kk) {
      const f32x4 xvv = *reinterpret_cast<const f32x4*>(&As[buf][lane][kk * 4]);
#pragma unroll
      for (int e = 0; e < FEW; ++e) {
        const f32x4 wv = *reinterpret_cast<const f32x4*>(wp + (size_t)e * D + kk * 4);
        acc[e] = fmaf(xvv.x, wv.x, acc[e]);
        acc[e] = fmaf(xvv.y, wv.y, acc[e]);
        acc[e] = fmaf(xvv.z, wv.z, acc[e]);
        acc[e] = fmaf(xvv.w, wv.w, acc[e]);
      }
    }
    __syncthreads();
    if (more) {
      *reinterpret_cast<f32x4*>(&As[buf ^ 1][lane][4 * w]) = na;
      *reinterpret_cast<f32x4*>(&As[buf ^ 1][lane][4 * (w + 8)]) = nb;
    }
    __syncthreads();
  }
  float* L = &As[0][0][0];
  *reinterpret_cast<f32x4*>(&L[lane * FLDT + w * FEW + 0]) =
      (f32x4){acc[0], acc[1], acc[2], acc[3]};
  *reinterpret_cast<f32x4*>(&L[lane * FLDT + w * FEW + 4]) =
      (f32x4){acc[4], acc[5], acc[6], acc[7]};
  __syncthreads();
  if (tid < FTOK) {
    const float* row = &L[tid * FLDT];
    float b0 = -INFINITY, b1 = -INFINITY;
    int i0 = 0, i1 = 0;
#pragma unroll
    for (int e = 0; e < NE; ++e) {
      const float val = row[e];
      if (val > b0) { b1 = b0; i1 = i0; b0 = val; i0 = e; }
      else if (val > b1) { b1 = val; i1 = e; }
    }
    const float e1 = expf(b1 - b0);
    const float inv = 1.f / (1.f + e1);
    const int tok = m0 + tid;
    out_probs[tok * 2 + 0] = inv;
    out_probs[tok * 2 + 1] = e1 * inv;
    out_idx[tok * 2 + 0] = (float)i0;
    out_idx[tok * 2 + 1] = (float)i1;
  }
}

extern "C" void kernel_launch(void* const* d_in, const int* in_sizes, int n_in,
                              void* d_out, int out_size, void* d_ws, size_t ws_size,
                              hipStream_t stream) {
  const float* x = (const float*)d_in[0];
  const float* W = (const float*)d_in[1];

  const int E = 64;
  const int D = in_sizes[1] / E;            // 4096
  const int nTok = in_sizes[0] / D;         // 16384

  float* probs = (float*)d_out;
  float* idxo  = (float*)d_out + (size_t)nTok * 2;

  const size_t wBytes = (size_t)E * D * sizeof(short);   // 512 KB per half
  if (ws_size >= 2 * wBytes) {
    u32* Wh = (u32*)d_ws;
    u32* Wl = (u32*)((char*)d_ws + wBytes);
    hipLaunchKernelGGL(wprep, dim3((E * D / 4) / 256), dim3(256), 0, stream,
                       W, (uint2*)Wh, (uint2*)Wl);
    hipLaunchKernelGGL(gemm_topk, dim3(nTok / TOK), dim3(THREADS), 0, stream,
                       x, Wh, Wl, probs, idxo, D);
  } else {
    hipLaunchKernelGGL(router_fused, dim3(nTok / FTOK), dim3(512), 0, stream,
                       x, W, probs, idxo, D);
  }
}